// Round 1
// baseline (342.271 us; speedup 1.0000x reference)
//
#include <hip/hip_runtime.h>

#define CROP   7
#define NBOX   512
#define BATCH  2
#define NLVL   4
#define CH     256
#define C4     (CH / 4)   // 64 float4 per cell

// total cells = NLVL*BATCH*NBOX*CROP*CROP = 200704
// total threads = cells * C4 = 12,845,056 ; blocks = 50,176 @ 256 thr

__global__ __launch_bounds__(256) void roi_align_kernel(
    const float* __restrict__ f2, const float* __restrict__ f3,
    const float* __restrict__ f4, const float* __restrict__ f5,
    const float* __restrict__ boxes, float4* __restrict__ out)
{
#pragma clang fp contract(off)
    const unsigned tid  = blockIdx.x * blockDim.x + threadIdx.x;
    const unsigned c4   = tid & (C4 - 1);
    const unsigned cell = tid >> 6;

    const unsigned j = cell % CROP;
    unsigned t = cell / CROP;
    const unsigned i = t % CROP;
    t /= CROP;                       // t = (l*BATCH + b)*NBOX + n
    const unsigned n = t % NBOX;
    t /= NBOX;
    const unsigned b = t % BATCH;
    const unsigned l = t / BATCH;    // 0..3  (level = l + 2)

    const float* feat;
    unsigned H;                      // H == W at every level
    if      (l == 0) { feat = f2; H = 256; }
    else if (l == 1) { feat = f3; H = 128; }
    else if (l == 2) { feat = f4; H = 64;  }
    else             { feat = f5; H = 32;  }
    const float inv_scale = 1.0f / (float)(4u << l);   // 1/2^level

    // box coords mapped to level (division by pow2 is exact; mul by exact recip ok)
    const float* bx = boxes + (((size_t)b * NBOX + n) << 2);
    const float y1 = bx[0] * inv_scale;
    const float x1 = bx[1] * inv_scale;
    const float y2 = bx[2] * inv_scale;
    const float x2 = bx[3] * inv_scale;

    // sample centers — match numpy: t = (i+0.5)/7 ; g = a + t*(b-a), no FMA
    const float ti = ((float)i + 0.5f) / 7.0f;
    const float tj = ((float)j + 0.5f) / 7.0f;
    const float gy = y1 + ti * (y2 - y1);
    const float gx = x1 + tj * (x2 - x1);

    const float y0 = fmaxf(floorf(gy), 0.0f);
    const float x0 = fmaxf(floorf(gx), 0.0f);
    const float ly = gy - y0;
    const float lx = gx - x0;

    const float Hm1 = (float)(H - 1);
    const int yi0 = (int)fminf(y0,        Hm1);
    const int yi1 = (int)fminf(y0 + 1.0f, Hm1);
    const int xi0 = (int)fminf(x0,        Hm1);
    const int xi1 = (int)fminf(x0 + 1.0f, Hm1);

    const float w00 = (1.0f - ly) * (1.0f - lx);
    const float w01 = (1.0f - ly) * lx;
    const float w10 = ly * (1.0f - lx);
    const float w11 = ly * lx;

    const float4* fp = (const float4*)feat;
    const size_t rowb = (size_t)b * H * H * C4;   // batch base, float4 units
    const float4 v00 = fp[rowb + ((size_t)yi0 * H + xi0) * C4 + c4];
    const float4 v01 = fp[rowb + ((size_t)yi0 * H + xi1) * C4 + c4];
    const float4 v10 = fp[rowb + ((size_t)yi1 * H + xi0) * C4 + c4];
    const float4 v11 = fp[rowb + ((size_t)yi1 * H + xi1) * C4 + c4];

    float4 r;
    r.x = w00 * v00.x + w01 * v01.x + w10 * v10.x + w11 * v11.x;
    r.y = w00 * v00.y + w01 * v01.y + w10 * v10.y + w11 * v11.y;
    r.z = w00 * v00.z + w01 * v01.z + w10 * v10.z + w11 * v11.z;
    r.w = w00 * v00.w + w01 * v01.w + w10 * v10.w + w11 * v11.w;

    out[tid] = r;
}

extern "C" void kernel_launch(void* const* d_in, const int* in_sizes, int n_in,
                              void* d_out, int out_size, void* d_ws, size_t ws_size,
                              hipStream_t stream) {
    const float* f2    = (const float*)d_in[0];
    const float* f3    = (const float*)d_in[1];
    const float* f4    = (const float*)d_in[2];
    const float* f5    = (const float*)d_in[3];
    const float* boxes = (const float*)d_in[4];
    float4* out = (float4*)d_out;

    const unsigned total_threads = NLVL * BATCH * NBOX * CROP * CROP * C4; // 12,845,056
    const unsigned block = 256;
    const unsigned grid  = total_threads / block;                          // 50,176

    roi_align_kernel<<<grid, block, 0, stream>>>(f2, f3, f4, f5, boxes, out);
}

// Round 3
// 332.908 us; speedup vs baseline: 1.0281x; 1.0281x over previous
//
#include <hip/hip_runtime.h>

#define CROP   7
#define NBOX   512
#define BATCH  2
#define NLVL   4
#define CH     256
#define C4     (CH / 4)   // 64 float4 per cell; one wave = one cell

typedef float nfloat4 __attribute__((ext_vector_type(4)));  // native vec for builtins

// Block = one (level, batch, box, i) row: 7 cells x 64 lanes = 448 threads.
// Grid = NLVL*BATCH*NBOX*CROP = 28,672 blocks.
// blockIdx swizzle: all 7 row-blocks of box q share (blockIdx % 8) == (q % 8),
// so one box stays on one XCD (round-robin dispatch heuristic) -> no duplicate
// corner fetches across per-XCD L2s.

__global__ __launch_bounds__(448) void roi_align_kernel(
    const float* __restrict__ f2, const float* __restrict__ f3,
    const float* __restrict__ f4, const float* __restrict__ f5,
    const float* __restrict__ boxes, nfloat4* __restrict__ out)
{
#pragma clang fp contract(off)
    const unsigned lane = threadIdx.x & 63;   // c4 channel-quad
    const unsigned j    = threadIdx.x >> 6;   // wave id = grid column 0..6

    // de-swizzle block index
    const unsigned g   = blockIdx.x;
    const unsigned xcd = g & 7;
    const unsigned rem = g >> 3;              // = (q>>3)*7 + i
    const unsigned q8  = rem / 7;
    const unsigned i   = rem - q8 * 7;
    const unsigned q   = (q8 << 3) | xcd;     // q = ((l*BATCH)+b)*NBOX + n
    const unsigned n   = q & (NBOX - 1);
    const unsigned b   = (q >> 9) & (BATCH - 1);
    const unsigned l   = q >> 10;             // 0..3 (level = l+2)

    const float* feat;
    unsigned H;                               // H == W at every level
    if      (l == 0) { feat = f2; H = 256; }
    else if (l == 1) { feat = f3; H = 128; }
    else if (l == 2) { feat = f4; H = 64;  }
    else             { feat = f5; H = 32;  }
    const float inv_scale = 1.0f / (float)(4u << l);   // 1/2^level (exact)

    const float* bx = boxes + (((size_t)b * NBOX + n) << 2);
    const float y1 = bx[0] * inv_scale;
    const float x1 = bx[1] * inv_scale;
    const float y2 = bx[2] * inv_scale;
    const float x2 = bx[3] * inv_scale;

    // sample centers — match numpy exactly: t=(k+0.5)/7 ; g = a + t*(b-a), no FMA
    const float ti = ((float)i + 0.5f) / 7.0f;
    const float tj = ((float)j + 0.5f) / 7.0f;
    const float gy = y1 + ti * (y2 - y1);
    const float gx = x1 + tj * (x2 - x1);

    const float y0 = fmaxf(floorf(gy), 0.0f);
    const float x0 = fmaxf(floorf(gx), 0.0f);
    const float ly = gy - y0;
    const float lx = gx - x0;

    const float Hm1 = (float)(H - 1);
    const int yi0 = (int)fminf(y0,        Hm1);
    const int yi1 = (int)fminf(y0 + 1.0f, Hm1);
    const int xi0 = (int)fminf(x0,        Hm1);
    const int xi1 = (int)fminf(x0 + 1.0f, Hm1);

    const float w00 = (1.0f - ly) * (1.0f - lx);
    const float w01 = (1.0f - ly) * lx;
    const float w10 = ly * (1.0f - lx);
    const float w11 = ly * lx;

    const nfloat4* fp = (const nfloat4*)feat;
    const size_t rowb = (size_t)b * H * H * C4;   // batch base in float4 units
    const nfloat4 v00 = fp[rowb + ((size_t)yi0 * H + xi0) * C4 + lane];
    const nfloat4 v01 = fp[rowb + ((size_t)yi0 * H + xi1) * C4 + lane];
    const nfloat4 v10 = fp[rowb + ((size_t)yi1 * H + xi0) * C4 + lane];
    const nfloat4 v11 = fp[rowb + ((size_t)yi1 * H + xi1) * C4 + lane];

    nfloat4 r;
    r.x = w00 * v00.x + w01 * v01.x + w10 * v10.x + w11 * v11.x;
    r.y = w00 * v00.y + w01 * v01.y + w10 * v10.y + w11 * v11.y;
    r.z = w00 * v00.z + w01 * v01.z + w10 * v10.z + w11 * v11.z;
    r.w = w00 * v00.w + w01 * v01.w + w10 * v10.w + w11 * v11.w;

    // out[l,b,n,i,j,c] — same flat layout as reference
    const size_t oidx = (((size_t)q * (CROP * CROP) + i * CROP + j) << 6) + lane;
    // non-temporal: don't let 205 MB of output evict the feature maps from L2/L3
    __builtin_nontemporal_store(r, &out[oidx]);
}

extern "C" void kernel_launch(void* const* d_in, const int* in_sizes, int n_in,
                              void* d_out, int out_size, void* d_ws, size_t ws_size,
                              hipStream_t stream) {
    const float* f2    = (const float*)d_in[0];
    const float* f3    = (const float*)d_in[1];
    const float* f4    = (const float*)d_in[2];
    const float* f5    = (const float*)d_in[3];
    const float* boxes = (const float*)d_in[4];
    nfloat4* out = (nfloat4*)d_out;

    const unsigned grid  = NLVL * BATCH * NBOX * CROP;  // 28,672 row-blocks
    const unsigned block = CROP * 64;                   // 448 threads

    roi_align_kernel<<<grid, block, 0, stream>>>(f2, f3, f4, f5, boxes, out);
}